// Round 6
// baseline (456.996 us; speedup 1.0000x reference)
//
#include <hip/hip_runtime.h>
#include <cstdint>
#include <cstddef>

// GCN_52012053955018 — round 10
//
// Round-9 post-mortem: place||dense = 138us (better than predicted; fusion +
// dbuf worked). Total stuck at 448 because (a) ~120us of dur_us is the
// harness's 800MB ws re-poison fill (uncontrollable floor, verified by
// round-8 arithmetic), (b) serial chain count->scan->place||dense->spmm0->
// walk1 ~330us.
//
// Round 10 (chain shortening):
//  * dense split in half: denseA || count, then scan, then denseB || place.
//    (count doesn't need scan; only place does.)
//  * RPB 128 -> 64: 1563 bins -> 2x blocks for spmm0/walk1, 19KB sort LDS,
//    shorter scans. BCAP 2368 = mu 2048 + 7 sigma.
//  * spmm0 stages its <=5 edges in named registers (e0..e4, no dynamic
//    indexing -> no scratch): kills the 2nd 29MB binbuf global pass.
//  * dense inner k-loop fully unrolled (VGPR headroom: was 24).
//  * prep standalone (must complete before dense reads W1T; same-kernel
//    fusion would race).
//  6 launches: prep -> count||denseA -> scan -> place||denseB -> spmm0 -> walk1.
//
// fast-path ws (floats):
//   [xw1 n*8][right n*8][h n*8][W1T 4096][VT 4096][VSQT 4096]
//   [hist nbins*NB][off nbins*NB][bintotal nbins]
//   [rowstart nbins*64][rowcnt nbins*64][align]
//   [binbuf nbins*BCAP u64][sortbuf nbins*BCAP u64]

#define NFEAT 512
#define NHID 8
#define NCLASS 16
#define RPB 64             // rows per bin; bin = row>>6
#define NB 512             // build blocks
#define BCAP 2368          // per-bin slots (mu=2048, +7 sigma)
#define NBINS_MAX 2048

#define DB_NODES 64
#define DB_CHUNK 32
#define DB_PAD 33
#define DB_BUF (DB_NODES * DB_PAD)   // 2112 floats per buffer

// ---------------- dense body: double-buffered, 1 barrier/chunk ----------------
__device__ __forceinline__ void dense_body2(
    int node0, int tid,
    const float* __restrict__ x,
    const float* __restrict__ W1T, const float* __restrict__ VT,
    const float* __restrict__ VSQT,
    const float* __restrict__ gamma, const float* __restrict__ beta,
    float* __restrict__ xw1, float* __restrict__ right, int n_nodes,
    float* xs)   // 2*DB_BUF floats
{
    const int lane = tid & 63;

    // wave-uniform j pair {j0, j0+4}: scalarized weight streams (s_load)
    const int j0 = __builtin_amdgcn_readfirstlane(tid >> 6);
    const float* __restrict__ w1a = W1T  + j0 * NFEAT;
    const float* __restrict__ w1b = W1T  + (j0 + 4) * NFEAT;
    const float* __restrict__ va  = VT   + j0 * NFEAT;
    const float* __restrict__ vb  = VT   + (j0 + 4) * NFEAT;
    const float* __restrict__ sa  = VSQT + j0 * NFEAT;
    const float* __restrict__ sb  = VSQT + (j0 + 4) * NFEAT;

    // staging geometry: 64 nodes x 32 floats = 512 float4 slots, 2/thread
    const int row0 = tid >> 3, row1 = row0 + 32;
    const int col  = tid & 7;
    int gr0 = node0 + row0; if (gr0 >= n_nodes) gr0 = n_nodes - 1;
    int gr1 = node0 + row1; if (gr1 >= n_nodes) gr1 = n_nodes - 1;
    const float4* __restrict__ p0 = (const float4*)(x + (size_t)gr0 * NFEAT) + col;
    const float4* __restrict__ p1 = (const float4*)(x + (size_t)gr1 * NFEAT) + col;
    const int b0 = row0 * DB_PAD + col * 4;
    const int b1 = row1 * DB_PAD + col * 4;

    float a1a = 0.f, a1b = 0.f;   // x@W1
    float ava = 0.f, avb = 0.f;   // x@V
    float a2a = 0.f, a2b = 0.f;   // x^2@V^2
    const int xbase = lane * DB_PAD;

    // prologue: stage chunk 0 into buf0
    {
        float4 c0 = p0[0], c1 = p1[0];
        xs[b0] = c0.x; xs[b0 + 1] = c0.y; xs[b0 + 2] = c0.z; xs[b0 + 3] = c0.w;
        xs[b1] = c1.x; xs[b1 + 1] = c1.y; xs[b1 + 2] = c1.z; xs[b1 + 3] = c1.w;
    }
    __syncthreads();

    for (int ch = 0; ch < NFEAT / DB_CHUNK; ++ch) {
        float4 n0, n1;
        const bool more = (ch + 1) < (NFEAT / DB_CHUNK);
        if (more) { n0 = p0[(ch + 1) * 8]; n1 = p1[(ch + 1) * 8]; }  // prefetch

        const float* xb = xs + (ch & 1) * DB_BUF + xbase;
        const int kof = ch * DB_CHUNK;
#pragma unroll
        for (int kk = 0; kk < DB_CHUNK / 4; ++kk) {
            const int kb = kof + kk * 4;
            float x0 = xb[kk * 4 + 0];
            float x1 = xb[kk * 4 + 1];
            float x2 = xb[kk * 4 + 2];
            float x3 = xb[kk * 4 + 3];
            float q0 = x0 * x0, q1 = x1 * x1, q2 = x2 * x2, q3 = x3 * x3;

            a1a += x0 * w1a[kb] + x1 * w1a[kb + 1] + x2 * w1a[kb + 2] + x3 * w1a[kb + 3];
            a1b += x0 * w1b[kb] + x1 * w1b[kb + 1] + x2 * w1b[kb + 2] + x3 * w1b[kb + 3];
            ava += x0 * va[kb]  + x1 * va[kb + 1]  + x2 * va[kb + 2]  + x3 * va[kb + 3];
            avb += x0 * vb[kb]  + x1 * vb[kb + 1]  + x2 * vb[kb + 2]  + x3 * vb[kb + 3];
            a2a += q0 * sa[kb]  + q1 * sa[kb + 1]  + q2 * sa[kb + 2]  + q3 * sa[kb + 3];
            a2b += q0 * sb[kb]  + q1 * sb[kb + 1]  + q2 * sb[kb + 2]  + q3 * sb[kb + 3];
        }

        if (more) {   // write prefetched chunk into the other buffer
            float* d = xs + ((ch + 1) & 1) * DB_BUF;
            d[b0] = n0.x; d[b0 + 1] = n0.y; d[b0 + 2] = n0.z; d[b0 + 3] = n0.w;
            d[b1] = n1.x; d[b1 + 1] = n1.y; d[b1 + 2] = n1.z; d[b1 + 3] = n1.w;
        }
        __syncthreads();
    }

    int node = node0 + lane;
    if (node < n_nodes) {
        float g0 = gamma[j0], g1 = gamma[j0 + 4];
        float b0_ = beta[j0], b1_ = beta[j0 + 4];
        xw1[node * 8 + j0]     = a1a;
        xw1[node * 8 + j0 + 4] = a1b;
        float ra = fmaxf(0.5f * (ava * ava - a2a), 0.f);
        float rb = fmaxf(0.5f * (avb * avb - a2b), 0.f);
        right[node * 8 + j0]     = 0.5f * (g0 * ra + b0_);
        right[node * 8 + j0 + 4] = 0.5f * (g1 * rb + b1_);
    }
}

// standalone dense (fallback path)
__global__ __launch_bounds__(256) void dense_kernel(
    const float* __restrict__ x,
    const float* __restrict__ W1T, const float* __restrict__ VT,
    const float* __restrict__ VSQT,
    const float* __restrict__ gamma, const float* __restrict__ beta,
    float* __restrict__ xw1, float* __restrict__ right, int n_nodes)
{
    __shared__ float xs[2 * DB_BUF];
    dense_body2(blockIdx.x * DB_NODES, threadIdx.x, x, W1T, VT, VSQT,
                gamma, beta, xw1, right, n_nodes, xs);
}

// ---------------- P0: weight transposes (+V^2) ----------------
__global__ __launch_bounds__(256) void prep_kernel(
    const float* __restrict__ W1, const float* __restrict__ V,
    float* __restrict__ W1T, float* __restrict__ VT, float* __restrict__ VSQT,
    uint4* __restrict__ zero_base, int zero_count16)
{
    int tid = blockIdx.x * 256 + threadIdx.x;
    if (tid < NFEAT * NHID) {
        int k = tid >> 3, j = tid & 7;
        W1T[j * NFEAT + k] = W1[tid];
        float vv = V[tid];
        VT[j * NFEAT + k] = vv;
        VSQT[j * NFEAT + k] = vv * vv;
    }
    int stride = gridDim.x * 256;
    for (int i = tid; i < zero_count16; i += stride)
        zero_base[i] = make_uint4(0u, 0u, 0u, 0u);
}

// ---------------- P1: denseA (first half) || count ----------------
__global__ __launch_bounds__(256) void count_denseA_kernel(
    const int* __restrict__ rows, int* __restrict__ hist,
    int chunk, int nbins, int e,
    const float* __restrict__ x, const float* __restrict__ W1T,
    const float* __restrict__ VT, const float* __restrict__ VSQT,
    const float* __restrict__ gamma, const float* __restrict__ beta,
    float* __restrict__ xw1, float* __restrict__ right,
    int n_nodes, int dblocksA)
{
    __shared__ float xs[2 * DB_BUF];          // 16896 B; count aliases as int
    const int bid = blockIdx.x;
    const int tid = threadIdx.x;

    if (bid < dblocksA) {
        dense_body2(bid * DB_NODES, tid, x, W1T, VT, VSQT,
                    gamma, beta, xw1, right, n_nodes, xs);
        return;
    }

    // ---- count role ----
    const int cb = bid - dblocksA;            // 0..NB-1
    int* histl = (int*)xs;                    // nbins ints (<= 2048)
    for (int i = tid; i < nbins; i += 256) histl[i] = 0;
    __syncthreads();

    const int base = cb * chunk;              // chunk % 4 == 0
    int lim = e - base; if (lim > chunk) lim = chunk; if (lim < 0) lim = 0;
    const int nq = lim >> 2;
    for (int q = tid; q < nq; q += 256) {
        int4 r4 = *(const int4*)(rows + base + q * 4);
        atomicAdd(&histl[r4.x >> 6], 1);
        atomicAdd(&histl[r4.y >> 6], 1);
        atomicAdd(&histl[r4.z >> 6], 1);
        atomicAdd(&histl[r4.w >> 6], 1);
    }
    const int rem = lim & 3;
    if (tid < rem) atomicAdd(&histl[rows[base + nq * 4 + tid] >> 6], 1);
    __syncthreads();
    for (int i = tid; i < nbins; i += 256)
        hist[(size_t)i * NB + cb] = histl[i];
}

// ---------------- P2: per-bin scan of NB counts -> off, bintotal ----------------
__global__ __launch_bounds__(NB) void scan_kernel(
    const int* __restrict__ hist, int* __restrict__ off,
    int* __restrict__ bintotal)
{
    __shared__ int sa[NB], sb[NB];
    const int bin = blockIdx.x;
    const int tid = threadIdx.x;
    const size_t base = (size_t)bin * NB;

    int h0 = hist[base + tid];
    sa[tid] = h0;
    __syncthreads();
    int* s = sa; int* d = sb;
    for (int o = 1; o < NB; o <<= 1) {
        d[tid] = s[tid] + (tid >= o ? s[tid - o] : 0);
        __syncthreads();
        int* t = s; s = d; d = t;
    }
    off[base + tid] = s[tid] - h0;             // exclusive
    if (tid == NB - 1) bintotal[bin] = s[NB - 1];
}

// ---------------- P3: denseB (second half) || place ----------------
__global__ __launch_bounds__(256) void place_denseB_kernel(
    const int* __restrict__ rows, const int* __restrict__ cols,
    const float* __restrict__ vals, const int* __restrict__ off,
    unsigned long long* __restrict__ binbuf,
    int chunk, int nbins, int e,
    const float* __restrict__ x, const float* __restrict__ W1T,
    const float* __restrict__ VT, const float* __restrict__ VSQT,
    const float* __restrict__ gamma, const float* __restrict__ beta,
    float* __restrict__ xw1, float* __restrict__ right,
    int n_nodes, int dblocksB, int nodeB0)
{
    __shared__ float xs[2 * DB_BUF];          // place aliases as int
    const int bid = blockIdx.x;
    const int tid = threadIdx.x;

    if (bid < dblocksB) {
        dense_body2(nodeB0 + bid * DB_NODES, tid, x, W1T, VT, VSQT,
                    gamma, beta, xw1, right, n_nodes, xs);
        return;
    }

    // ---- place role ----
    const int cb = bid - dblocksB;            // 0..NB-1
    int* cur = (int*)xs;                      // nbins ints (<= 2048)
    for (int i = tid; i < nbins; i += 256)
        cur[i] = off[(size_t)i * NB + cb];
    __syncthreads();

    const int base = cb * chunk;
    int lim = e - base; if (lim > chunk) lim = chunk; if (lim < 0) lim = 0;
    const int nq = lim >> 2;
    for (int q = tid; q < nq; q += 256) {
        int i = base + q * 4;
        int4   r4 = *(const int4*)(rows + i);
        int4   c4 = *(const int4*)(cols + i);
        float4 v4 = *(const float4*)(vals + i);
#pragma unroll
        for (int u = 0; u < 4; ++u) {
            int r = (&r4.x)[u], c = (&c4.x)[u];
            float v = (&v4.x)[u];
            int bin = r >> 6;
            int slot = atomicAdd(&cur[bin], 1);      // LDS int atomic (native)
            if (slot < BCAP) {
                unsigned long long ev =
                    ((unsigned long long)__float_as_uint(v) << 32) |
                    ((unsigned)(r & (RPB - 1)) << 17) | (unsigned)(unsigned int)c;
                binbuf[(size_t)bin * BCAP + slot] = ev;
            }
        }
    }
    const int rem = lim & 3;
    if (tid < rem) {
        int i = base + nq * 4 + tid;
        int r = rows[i];
        int bin = r >> 6;
        int slot = atomicAdd(&cur[bin], 1);
        if (slot < BCAP) {
            unsigned long long ev =
                ((unsigned long long)__float_as_uint(vals[i]) << 32) |
                ((unsigned)(r & (RPB - 1)) << 17) | (unsigned)(unsigned int)cols[i];
            binbuf[(size_t)bin * BCAP + slot] = ev;
        }
    }
}

// ---------------- spmm0: reg-staged sort + writeback + walk + h epilogue ----------------
__global__ __launch_bounds__(512) void binspmm0_kernel(
    const unsigned long long* __restrict__ binbuf,
    const int* __restrict__ bintotal,
    unsigned long long* __restrict__ sortbuf,
    int* __restrict__ rowstart, int* __restrict__ rowcnt,
    const float* __restrict__ src,
    const float* __restrict__ b1, const float* __restrict__ right,
    float* __restrict__ dst, int n)
{
    __shared__ unsigned long long sorted[BCAP];   // 18944 B
    __shared__ int hcnt[RPB];
    __shared__ int hstart[RPB];
    __shared__ int hcur[RPB];
    const int bin = blockIdx.x;
    const int tid = threadIdx.x;

    if (tid < RPB) hcnt[tid] = 0;
    __syncthreads();

    int total = bintotal[bin];
    if (total > BCAP) total = BCAP;
    const unsigned long long* bb = binbuf + (size_t)bin * BCAP;

    // pass a: load edges into named regs (<=5) + per-row histogram
    const int s0 = tid, s1 = tid + 512, s2 = tid + 1024, s3 = tid + 1536, s4 = tid + 2048;
    unsigned long long e0 = 0, e1 = 0, e2 = 0, e3 = 0, e4 = 0;
    if (s0 < total) { e0 = bb[s0]; atomicAdd(&hcnt[(int)((e0 >> 17) & (RPB - 1))], 1); }
    if (s1 < total) { e1 = bb[s1]; atomicAdd(&hcnt[(int)((e1 >> 17) & (RPB - 1))], 1); }
    if (s2 < total) { e2 = bb[s2]; atomicAdd(&hcnt[(int)((e2 >> 17) & (RPB - 1))], 1); }
    if (s3 < total) { e3 = bb[s3]; atomicAdd(&hcnt[(int)((e3 >> 17) & (RPB - 1))], 1); }
    if (s4 < total) { e4 = bb[s4]; atomicAdd(&hcnt[(int)((e4 >> 17) & (RPB - 1))], 1); }
    __syncthreads();

    // pass b: 64-wide exclusive scan
    if (tid < RPB) hstart[tid] = hcnt[tid];
    __syncthreads();
    for (int o = 1; o < RPB; o <<= 1) {
        int t = 0;
        if (tid < RPB) t = hstart[tid] + (tid >= o ? hstart[tid - o] : 0);
        __syncthreads();
        if (tid < RPB) hstart[tid] = t;
        __syncthreads();
    }
    if (tid < RPB) {
        int ex = hstart[tid] - hcnt[tid];
        hstart[tid] = ex;
        hcur[tid] = ex;
    }
    __syncthreads();

    // pass c: scatter from regs into row-sorted LDS
    if (s0 < total) { int rl = (int)((e0 >> 17) & (RPB - 1)); sorted[atomicAdd(&hcur[rl], 1)] = e0; }
    if (s1 < total) { int rl = (int)((e1 >> 17) & (RPB - 1)); sorted[atomicAdd(&hcur[rl], 1)] = e1; }
    if (s2 < total) { int rl = (int)((e2 >> 17) & (RPB - 1)); sorted[atomicAdd(&hcur[rl], 1)] = e2; }
    if (s3 < total) { int rl = (int)((e3 >> 17) & (RPB - 1)); sorted[atomicAdd(&hcur[rl], 1)] = e3; }
    if (s4 < total) { int rl = (int)((e4 >> 17) & (RPB - 1)); sorted[atomicAdd(&hcur[rl], 1)] = e4; }
    __syncthreads();

    // writeback for walk1 (coalesced)
    for (int s = tid; s < total; s += 512)
        sortbuf[(size_t)bin * BCAP + s] = sorted[s];
    if (tid < RPB) {
        rowstart[bin * RPB + tid] = hstart[tid];
        rowcnt[bin * RPB + tid]   = hcnt[tid];
    }

    // pass d: 8 lanes/row register walk + h epilogue
    const int rl = tid >> 3, l = tid & 7;
    const int st = hstart[rl], cn = hcnt[rl];
    float a0 = 0.f, a1 = 0.f, a2 = 0.f, a3 = 0.f;
    float a4 = 0.f, a5 = 0.f, a6 = 0.f, a7 = 0.f;
    for (int i = st + l; i < st + cn; i += 8) {
        unsigned long long ev = sorted[i];
        int col = (int)(ev & 0x1FFFFu);
        float v = __uint_as_float((unsigned)(ev >> 32));
        const float4* sp = (const float4*)(src + (size_t)col * 8);
        float4 lo = sp[0], hi = sp[1];
        a0 += v * lo.x; a1 += v * lo.y; a2 += v * lo.z; a3 += v * lo.w;
        a4 += v * hi.x; a5 += v * hi.y; a6 += v * hi.z; a7 += v * hi.w;
    }
#pragma unroll
    for (int o2 = 1; o2 < 8; o2 <<= 1) {
        a0 += __shfl_xor(a0, o2); a1 += __shfl_xor(a1, o2);
        a2 += __shfl_xor(a2, o2); a3 += __shfl_xor(a3, o2);
        a4 += __shfl_xor(a4, o2); a5 += __shfl_xor(a5, o2);
        a6 += __shfl_xor(a6, o2); a7 += __shfl_xor(a7, o2);
    }

    const int g = bin * RPB + rl;
    if (g >= n) return;

    // lane l owns h feature l
    float s = l < 4 ? (l < 2 ? (l == 0 ? a0 : a1) : (l == 2 ? a2 : a3))
                    : (l < 6 ? (l == 4 ? a4 : a5) : (l == 6 ? a6 : a7));
    float hv = 0.5f * fmaxf(s + b1[l], 0.f) + right[(size_t)g * 8 + l];
    dst[(size_t)g * 8 + l] = hv;
}

// ---------------- walk1: lean walk over pre-sorted edges + final epilogue ----------------
__global__ __launch_bounds__(256) void walk1_kernel(
    const unsigned long long* __restrict__ sortbuf,
    const int* __restrict__ rowstart, const int* __restrict__ rowcnt,
    const float* __restrict__ src,
    const float* __restrict__ W2, const float* __restrict__ b2,
    float* __restrict__ out, int n)
{
    const int bin = blockIdx.x;
    const int tid = threadIdx.x;
    const int rl = tid >> 2, l = tid & 3;     // 64 rows x 4 lanes

    const int st = rowstart[bin * RPB + rl];
    const int cn = rowcnt[bin * RPB + rl];
    const unsigned long long* bb = sortbuf + (size_t)bin * BCAP;

    float a0 = 0.f, a1 = 0.f, a2 = 0.f, a3 = 0.f;
    float a4 = 0.f, a5 = 0.f, a6 = 0.f, a7 = 0.f;
    for (int i = st + l; i < st + cn; i += 4) {
        unsigned long long ev = bb[i];            // quad reads 32B contiguous
        int col = (int)(ev & 0x1FFFFu);
        float v = __uint_as_float((unsigned)(ev >> 32));
        const float4* sp = (const float4*)(src + (size_t)col * 8);
        float4 lo = sp[0], hi = sp[1];
        a0 += v * lo.x; a1 += v * lo.y; a2 += v * lo.z; a3 += v * lo.w;
        a4 += v * hi.x; a5 += v * hi.y; a6 += v * hi.z; a7 += v * hi.w;
    }
#pragma unroll
    for (int o2 = 1; o2 < 4; o2 <<= 1) {
        a0 += __shfl_xor(a0, o2); a1 += __shfl_xor(a1, o2);
        a2 += __shfl_xor(a2, o2); a3 += __shfl_xor(a3, o2);
        a4 += __shfl_xor(a4, o2); a5 += __shfl_xor(a5, o2);
        a6 += __shfl_xor(a6, o2); a7 += __shfl_xor(a7, o2);
    }

    const int g = bin * RPB + rl;
    if (g >= n) return;

    float hv[NHID] = {a0, a1, a2, a3, a4, a5, a6, a7};
    float z[NCLASS];
#pragma unroll
    for (int cc = 0; cc < NCLASS; ++cc) z[cc] = b2[cc];
#pragma unroll
    for (int j = 0; j < NHID; ++j) {
#pragma unroll
        for (int cc = 0; cc < NCLASS; ++cc)
            z[cc] += hv[j] * W2[j * NCLASS + cc];
    }
    float m = z[0];
#pragma unroll
    for (int cc = 1; cc < NCLASS; ++cc) m = fmaxf(m, z[cc]);
    float s = 0.f;
#pragma unroll
    for (int cc = 0; cc < NCLASS; ++cc) s += __expf(z[cc] - m);
    float lse = m + __logf(s);
    float o0, o1, o2, o3;
    if (l == 0)      { o0 = z[0];  o1 = z[1];  o2 = z[2];  o3 = z[3];  }
    else if (l == 1) { o0 = z[4];  o1 = z[5];  o2 = z[6];  o3 = z[7];  }
    else if (l == 2) { o0 = z[8];  o1 = z[9];  o2 = z[10]; o3 = z[11]; }
    else             { o0 = z[12]; o1 = z[13]; o2 = z[14]; o3 = z[15]; }
    *(float4*)(out + (size_t)g * NCLASS + 4 * l) =
        make_float4(o0 - lse, o1 - lse, o2 - lse, o3 - lse);
}

// ---------------- fallback path ----------------
__global__ __launch_bounds__(256) void spmm8_kernel(
    const int* __restrict__ rows, const int* __restrict__ cols,
    const float* __restrict__ vals, const float* __restrict__ src,
    float* __restrict__ acc, int n_edges)
{
    int tid = blockIdx.x * 256 + threadIdx.x;
    int e = tid >> 1;
    if (e >= n_edges) return;
    int hh = tid & 1;
    int r = rows[e], c = cols[e];
    float v = vals[e];
    float4 f = ((const float4*)src)[c * 2 + hh];
    float* d = acc + (size_t)r * NHID + hh * 4;
    unsafeAtomicAdd(d + 0, v * f.x);
    unsafeAtomicAdd(d + 1, v * f.y);
    unsafeAtomicAdd(d + 2, v * f.z);
    unsafeAtomicAdd(d + 3, v * f.w);
}

__global__ __launch_bounds__(256) void mid_kernel(
    const float* __restrict__ acc1, const float* __restrict__ right,
    const float* __restrict__ b1, float* __restrict__ h, int n4)
{
    int i = blockIdx.x * 256 + threadIdx.x;
    if (i >= n4) return;
    float4 a = ((const float4*)acc1)[i];
    float4 r = ((const float4*)right)[i];
    float4 b = ((const float4*)b1)[i & 1];
    float4 o;
    o.x = 0.5f * fmaxf(a.x + b.x, 0.f) + r.x;
    o.y = 0.5f * fmaxf(a.y + b.y, 0.f) + r.y;
    o.z = 0.5f * fmaxf(a.z + b.z, 0.f) + r.z;
    o.w = 0.5f * fmaxf(a.w + b.w, 0.f) + r.w;
    ((float4*)h)[i] = o;
}

__global__ __launch_bounds__(256) void final_kernel(
    const float* __restrict__ acc2, const float* __restrict__ W2,
    const float* __restrict__ b2, float* __restrict__ out, int n_nodes)
{
    int node = blockIdx.x * 256 + threadIdx.x;
    if (node >= n_nodes) return;
    float4 h0 = ((const float4*)acc2)[(size_t)node * 2];
    float4 h1 = ((const float4*)acc2)[(size_t)node * 2 + 1];
    float hv[NHID] = {h0.x, h0.y, h0.z, h0.w, h1.x, h1.y, h1.z, h1.w};
    float z[NCLASS];
#pragma unroll
    for (int c = 0; c < NCLASS; ++c) z[c] = b2[c];
#pragma unroll
    for (int j = 0; j < NHID; ++j) {
#pragma unroll
        for (int c = 0; c < NCLASS; ++c) z[c] += hv[j] * W2[j * NCLASS + c];
    }
    float m = z[0];
#pragma unroll
    for (int c = 1; c < NCLASS; ++c) m = fmaxf(m, z[c]);
    float s = 0.f;
#pragma unroll
    for (int c = 0; c < NCLASS; ++c) s += __expf(z[c] - m);
    float l = m + __logf(s);
    float4* o = (float4*)(out + (size_t)node * NCLASS);
#pragma unroll
    for (int q = 0; q < 4; ++q) {
        float4 tq;
        tq.x = z[4 * q + 0] - l;
        tq.y = z[4 * q + 1] - l;
        tq.z = z[4 * q + 2] - l;
        tq.w = z[4 * q + 3] - l;
        o[q] = tq;
    }
}

extern "C" void kernel_launch(void* const* d_in, const int* in_sizes, int n_in,
                              void* d_out, int out_size, void* d_ws, size_t ws_size,
                              hipStream_t stream)
{
    const float* x     = (const float*)d_in[0];
    const int*   rows  = (const int*)  d_in[1];
    const int*   cols  = (const int*)  d_in[2];
    const float* vals  = (const float*)d_in[3];
    const float* W1    = (const float*)d_in[4];
    const float* b1    = (const float*)d_in[5];
    const float* W2    = (const float*)d_in[6];
    const float* b2    = (const float*)d_in[7];
    const float* V     = (const float*)d_in[8];
    const float* gamma = (const float*)d_in[9];
    const float* beta  = (const float*)d_in[10];

    const int n = in_sizes[0] / NFEAT;   // 100000
    const int e = in_sizes[1];           // 3200000
    const int nbins = (n + RPB - 1) / RPB;             // 1563
    const int dblocks = (n + DB_NODES - 1) / DB_NODES; // 1563
    const int dblocksA = dblocks / 2;                  // 781
    const int nodeB0 = dblocksA * DB_NODES;            // 49984
    const int dblocksB = dblocks - dblocksA;           // 782

    float* ws = (float*)d_ws;

    // ---- fast-path layout (floats) ----
    float* xw1   = ws;                         // n*8
    float* right = ws + (size_t)n * 8;         // n*8
    float* h     = ws + (size_t)n * 16;        // n*8
    float* W1T   = ws + (size_t)n * 24;        // 4096
    float* VT    = W1T + NFEAT * NHID;
    float* VSQT  = VT + NFEAT * NHID;
    const size_t fixedf = (size_t)n * 24 + 3 * NFEAT * NHID;
    int* hist     = (int*)(ws + fixedf);                       // nbins*NB
    int* off      = hist + (size_t)nbins * NB;                 // nbins*NB
    int* bintotal = off + (size_t)nbins * NB;                  // nbins
    int* rowstart = bintotal + nbins;                          // nbins*RPB
    int* rowcnt   = rowstart + (size_t)nbins * RPB;            // nbins*RPB
    size_t bb_off = (fixedf + 2ull * nbins * NB + nbins + 2ull * nbins * RPB + 1)
                    & ~(size_t)1;
    unsigned long long* binbuf  = (unsigned long long*)(ws + bb_off);
    unsigned long long* sortbuf = binbuf + (size_t)nbins * BCAP;

    const size_t needf = bb_off + 4ull * nbins * BCAP;
    const bool use_fast =
        (n <= (1 << 17)) && (nbins <= NBINS_MAX) && (needf * 4 <= ws_size);

    if (use_fast) {
        // chunk: multiple of 4 so int4/float4 edge loads stay 16B-aligned
        int chunk = ((e + NB - 1) / NB + 3) & ~3;

        prep_kernel<<<16, 256, 0, stream>>>(
            W1, V, W1T, VT, VSQT, (uint4*)ws, 0);

        count_denseA_kernel<<<dblocksA + NB, 256, 0, stream>>>(
            rows, hist, chunk, nbins, e,
            x, W1T, VT, VSQT, gamma, beta, xw1, right, n, dblocksA);

        scan_kernel<<<nbins, NB, 0, stream>>>(hist, off, bintotal);

        place_denseB_kernel<<<dblocksB + NB, 256, 0, stream>>>(
            rows, cols, vals, off, binbuf, chunk, nbins, e,
            x, W1T, VT, VSQT, gamma, beta, xw1, right, n, dblocksB, nodeB0);

        binspmm0_kernel<<<nbins, 512, 0, stream>>>(
            binbuf, bintotal, sortbuf, rowstart, rowcnt,
            xw1, b1, right, h, n);

        walk1_kernel<<<nbins, 256, 0, stream>>>(
            sortbuf, rowstart, rowcnt, h, W2, b2, (float*)d_out, n);
    } else {
        // fallback: atomic spmm path (acc1/acc2 lead the ws)
        float* f_acc1  = ws;
        float* f_acc2  = ws + (size_t)n * 8;
        float* f_xw1   = ws + (size_t)n * 16;
        float* f_right = ws + (size_t)n * 24;
        float* f_h     = ws + (size_t)n * 32;
        float* f_W1T   = ws + (size_t)n * 40;
        float* f_VT    = f_W1T + NFEAT * NHID;
        float* f_VSQT  = f_VT + NFEAT * NHID;

        prep_kernel<<<(n * 4 + 255) / 256, 256, 0, stream>>>(
            W1, V, f_W1T, f_VT, f_VSQT, (uint4*)ws, n * 4);

        dense_kernel<<<dblocks, 256, 0, stream>>>(
            x, f_W1T, f_VT, f_VSQT, gamma, beta, f_xw1, f_right, n);

        spmm8_kernel<<<(e * 2 + 255) / 256, 256, 0, stream>>>(rows, cols, vals, f_xw1, f_acc1, e);
        mid_kernel<<<(n * 2 + 255) / 256, 256, 0, stream>>>(f_acc1, f_right, b1, f_h, n * 2);
        spmm8_kernel<<<(e * 2 + 255) / 256, 256, 0, stream>>>(rows, cols, vals, f_h, f_acc2, e);
        final_kernel<<<(n + 255) / 256, 256, 0, stream>>>(f_acc2, W2, b2, (float*)d_out, n);
    }
}

// Round 7
// 452.226 us; speedup vs baseline: 1.0105x; 1.0105x over previous
//
#include <hip/hip_runtime.h>
#include <cstdint>
#include <cstddef>

// GCN_52012053955018 — round 11
//
// Round-10 post-mortem: dense split was neutral (448->457) — each half's
// sparse partner no longer fully hidden. Floor = ~120us ws re-poison fill
// + ~330us chain. Remaining chain inefficiencies:
//  (1) dense latency-bound: DB_PAD=33 -> lane rows 132B-aligned -> LDS reads
//      are 32x ds_read_b32/chunk (can't be b128), 2x LDS issue + 4x lgkmcnt
//      syncs vs b128. VALUBusy 19% vs ~65% theory.
//  (2) spmm walks: dependent ev->gather chains, ~4 serial L2 round trips.
//
// Round 11:
//  * round-9 chain shape (best measured): count+prep -> scan ->
//    place||full-dense -> spmm0 -> walk1 (5 launches).
//  * dense: DB_PAD=36 (144B, 16B-aligned; b128 bank aliasing 2-way = free),
//    explicit float4 LDS read/write -> ds_read_b128/ds_write_b128.
//  * both walks: 4-deep batched predicated gathers (all ev loads, then all
//    feature gathers, then FMAs; invalid slots decode v=0/col=0 -> add 0).
//  * walk1 epilogue: 8 lanes/row, each computes 2 classes; 8-lane shfl
//    max/sum for log-softmax (no idle lanes, 2 exps/lane).
//
// fast-path ws (floats):
//   [xw1 n*8][right n*8][h n*8][W1T 4096][VT 4096][VSQT 4096]
//   [hist nbins*NB][off nbins*NB][bintotal nbins]
//   [rowstart nbins*64][rowcnt nbins*64][align]
//   [binbuf nbins*BCAP u64][sortbuf nbins*BCAP u64]

#define NFEAT 512
#define NHID 8
#define NCLASS 16
#define RPB 64             // rows per bin; bin = row>>6
#define NB 512             // build blocks
#define BCAP 2368          // per-bin slots (mu=2048, +7 sigma)
#define NBINS_MAX 2048

#define DB_NODES 64
#define DB_CHUNK 32
#define DB_PAD 36                     // 144B row stride: 16B-aligned -> b128
#define DB_BUF (DB_NODES * DB_PAD)    // 2304 floats per buffer

// ---------------- dense body: double-buffered, b128 LDS, 1 barrier/chunk ----------------
__device__ __forceinline__ void dense_body2(
    int node0, int tid,
    const float* __restrict__ x,
    const float* __restrict__ W1T, const float* __restrict__ VT,
    const float* __restrict__ VSQT,
    const float* __restrict__ gamma, const float* __restrict__ beta,
    float* __restrict__ xw1, float* __restrict__ right, int n_nodes,
    float* xs)   // 2*DB_BUF floats
{
    const int lane = tid & 63;

    // wave-uniform j pair {j0, j0+4}: scalarized weight streams (s_load)
    const int j0 = __builtin_amdgcn_readfirstlane(tid >> 6);
    const float* __restrict__ w1a = W1T  + j0 * NFEAT;
    const float* __restrict__ w1b = W1T  + (j0 + 4) * NFEAT;
    const float* __restrict__ va  = VT   + j0 * NFEAT;
    const float* __restrict__ vb  = VT   + (j0 + 4) * NFEAT;
    const float* __restrict__ sa  = VSQT + j0 * NFEAT;
    const float* __restrict__ sb  = VSQT + (j0 + 4) * NFEAT;

    // staging geometry: 64 nodes x 32 floats = 512 float4 slots, 2/thread
    const int row0 = tid >> 3, row1 = row0 + 32;
    const int col  = tid & 7;
    int gr0 = node0 + row0; if (gr0 >= n_nodes) gr0 = n_nodes - 1;
    int gr1 = node0 + row1; if (gr1 >= n_nodes) gr1 = n_nodes - 1;
    const float4* __restrict__ p0 = (const float4*)(x + (size_t)gr0 * NFEAT) + col;
    const float4* __restrict__ p1 = (const float4*)(x + (size_t)gr1 * NFEAT) + col;
    const int b0 = row0 * DB_PAD + col * 4;   // 16B-aligned
    const int b1 = row1 * DB_PAD + col * 4;

    float a1a = 0.f, a1b = 0.f;   // x@W1
    float ava = 0.f, avb = 0.f;   // x@V
    float a2a = 0.f, a2b = 0.f;   // x^2@V^2
    const int xbase = lane * DB_PAD;

    // prologue: stage chunk 0 into buf0 (ds_write_b128)
    {
        float4 c0 = p0[0], c1 = p1[0];
        *(float4*)(xs + b0) = c0;
        *(float4*)(xs + b1) = c1;
    }
    __syncthreads();

    for (int ch = 0; ch < NFEAT / DB_CHUNK; ++ch) {
        float4 n0, n1;
        const bool more = (ch + 1) < (NFEAT / DB_CHUNK);
        if (more) { n0 = p0[(ch + 1) * 8]; n1 = p1[(ch + 1) * 8]; }  // prefetch

        const float* xb = xs + (ch & 1) * DB_BUF + xbase;
        const int kof = ch * DB_CHUNK;
#pragma unroll
        for (int kk = 0; kk < DB_CHUNK / 4; ++kk) {
            const int kb = kof + kk * 4;
            float4 xv = *(const float4*)(xb + kk * 4);   // ds_read_b128
            float x0 = xv.x, x1 = xv.y, x2 = xv.z, x3 = xv.w;
            float q0 = x0 * x0, q1 = x1 * x1, q2 = x2 * x2, q3 = x3 * x3;

            a1a += x0 * w1a[kb] + x1 * w1a[kb + 1] + x2 * w1a[kb + 2] + x3 * w1a[kb + 3];
            a1b += x0 * w1b[kb] + x1 * w1b[kb + 1] + x2 * w1b[kb + 2] + x3 * w1b[kb + 3];
            ava += x0 * va[kb]  + x1 * va[kb + 1]  + x2 * va[kb + 2]  + x3 * va[kb + 3];
            avb += x0 * vb[kb]  + x1 * vb[kb + 1]  + x2 * vb[kb + 2]  + x3 * vb[kb + 3];
            a2a += q0 * sa[kb]  + q1 * sa[kb + 1]  + q2 * sa[kb + 2]  + q3 * sa[kb + 3];
            a2b += q0 * sb[kb]  + q1 * sb[kb + 1]  + q2 * sb[kb + 2]  + q3 * sb[kb + 3];
        }

        if (more) {   // write prefetched chunk into the other buffer
            float* d = xs + ((ch + 1) & 1) * DB_BUF;
            *(float4*)(d + b0) = n0;
            *(float4*)(d + b1) = n1;
        }
        __syncthreads();
    }

    int node = node0 + lane;
    if (node < n_nodes) {
        float g0 = gamma[j0], g1 = gamma[j0 + 4];
        float b0_ = beta[j0], b1_ = beta[j0 + 4];
        xw1[node * 8 + j0]     = a1a;
        xw1[node * 8 + j0 + 4] = a1b;
        float ra = fmaxf(0.5f * (ava * ava - a2a), 0.f);
        float rb = fmaxf(0.5f * (avb * avb - a2b), 0.f);
        right[node * 8 + j0]     = 0.5f * (g0 * ra + b0_);
        right[node * 8 + j0 + 4] = 0.5f * (g1 * rb + b1_);
    }
}

// standalone dense (fallback path)
__global__ __launch_bounds__(256) void dense_kernel(
    const float* __restrict__ x,
    const float* __restrict__ W1T, const float* __restrict__ VT,
    const float* __restrict__ VSQT,
    const float* __restrict__ gamma, const float* __restrict__ beta,
    float* __restrict__ xw1, float* __restrict__ right, int n_nodes)
{
    __shared__ float xs[2 * DB_BUF];
    dense_body2(blockIdx.x * DB_NODES, threadIdx.x, x, W1T, VT, VSQT,
                gamma, beta, xw1, right, n_nodes, xs);
}

// ---------------- P1: count (bin histogram) + weight prep ----------------
__global__ __launch_bounds__(256) void count_prep_kernel(
    const int* __restrict__ rows, int* __restrict__ hist,
    int chunk, int nbins, int e,
    const float* __restrict__ W1, const float* __restrict__ V,
    float* __restrict__ W1T, float* __restrict__ VT, float* __restrict__ VSQT)
{
    __shared__ int histl[NBINS_MAX];
    const int bid = blockIdx.x;
    const int tid = threadIdx.x;

    // prep role folded into first 16 blocks (4096 elements)
    int gt = bid * 256 + tid;
    if (gt < NFEAT * NHID) {
        int k = gt >> 3, j = gt & 7;
        W1T[j * NFEAT + k] = W1[gt];
        float vv = V[gt];
        VT[j * NFEAT + k] = vv;
        VSQT[j * NFEAT + k] = vv * vv;
    }

    for (int i = tid; i < nbins; i += 256) histl[i] = 0;
    __syncthreads();

    const int base = bid * chunk;             // chunk % 4 == 0
    int lim = e - base; if (lim > chunk) lim = chunk; if (lim < 0) lim = 0;
    const int nq = lim >> 2;
    for (int q = tid; q < nq; q += 256) {
        int4 r4 = *(const int4*)(rows + base + q * 4);
        atomicAdd(&histl[r4.x >> 6], 1);
        atomicAdd(&histl[r4.y >> 6], 1);
        atomicAdd(&histl[r4.z >> 6], 1);
        atomicAdd(&histl[r4.w >> 6], 1);
    }
    const int rem = lim & 3;
    if (tid < rem) atomicAdd(&histl[rows[base + nq * 4 + tid] >> 6], 1);
    __syncthreads();
    for (int i = tid; i < nbins; i += 256)
        hist[(size_t)i * NB + bid] = histl[i];
}

// ---------------- P2: per-bin scan of NB counts -> off, bintotal ----------------
__global__ __launch_bounds__(NB) void scan_kernel(
    const int* __restrict__ hist, int* __restrict__ off,
    int* __restrict__ bintotal)
{
    __shared__ int sa[NB], sb[NB];
    const int bin = blockIdx.x;
    const int tid = threadIdx.x;
    const size_t base = (size_t)bin * NB;

    int h0 = hist[base + tid];
    sa[tid] = h0;
    __syncthreads();
    int* s = sa; int* d = sb;
    for (int o = 1; o < NB; o <<= 1) {
        d[tid] = s[tid] + (tid >= o ? s[tid - o] : 0);
        __syncthreads();
        int* t = s; s = d; d = t;
    }
    off[base + tid] = s[tid] - h0;             // exclusive
    if (tid == NB - 1) bintotal[bin] = s[NB - 1];
}

// ---------------- P3: full dense (blocks 0..dblocks-1) || place (rest) ----------------
__global__ __launch_bounds__(256) void place_dense_kernel(
    const int* __restrict__ rows, const int* __restrict__ cols,
    const float* __restrict__ vals, const int* __restrict__ off,
    unsigned long long* __restrict__ binbuf,
    int chunk, int nbins, int e,
    const float* __restrict__ x, const float* __restrict__ W1T,
    const float* __restrict__ VT, const float* __restrict__ VSQT,
    const float* __restrict__ gamma, const float* __restrict__ beta,
    float* __restrict__ xw1, float* __restrict__ right,
    int n_nodes, int dblocks)
{
    __shared__ float xs[2 * DB_BUF];          // 18432 B; place aliases as int
    const int bid = blockIdx.x;
    const int tid = threadIdx.x;

    if (bid < dblocks) {
        dense_body2(bid * DB_NODES, tid, x, W1T, VT, VSQT,
                    gamma, beta, xw1, right, n_nodes, xs);
        return;
    }

    // ---- place role ----
    const int cb = bid - dblocks;             // 0..NB-1
    int* cur = (int*)xs;                      // nbins ints (<= 2048)
    for (int i = tid; i < nbins; i += 256)
        cur[i] = off[(size_t)i * NB + cb];
    __syncthreads();

    const int base = cb * chunk;
    int lim = e - base; if (lim > chunk) lim = chunk; if (lim < 0) lim = 0;
    const int nq = lim >> 2;
    for (int q = tid; q < nq; q += 256) {
        int i = base + q * 4;
        int4   r4 = *(const int4*)(rows + i);
        int4   c4 = *(const int4*)(cols + i);
        float4 v4 = *(const float4*)(vals + i);
#pragma unroll
        for (int u = 0; u < 4; ++u) {
            int r = (&r4.x)[u], c = (&c4.x)[u];
            float v = (&v4.x)[u];
            int bin = r >> 6;
            int slot = atomicAdd(&cur[bin], 1);      // LDS int atomic (native)
            if (slot < BCAP) {
                unsigned long long ev =
                    ((unsigned long long)__float_as_uint(v) << 32) |
                    ((unsigned)(r & (RPB - 1)) << 17) | (unsigned)(unsigned int)c;
                binbuf[(size_t)bin * BCAP + slot] = ev;
            }
        }
    }
    const int rem = lim & 3;
    if (tid < rem) {
        int i = base + nq * 4 + tid;
        int r = rows[i];
        int bin = r >> 6;
        int slot = atomicAdd(&cur[bin], 1);
        if (slot < BCAP) {
            unsigned long long ev =
                ((unsigned long long)__float_as_uint(vals[i]) << 32) |
                ((unsigned)(r & (RPB - 1)) << 17) | (unsigned)(unsigned int)cols[i];
            binbuf[(size_t)bin * BCAP + slot] = ev;
        }
    }
}

// ---------------- spmm0: reg-staged sort + writeback + batched walk + h epilogue ----------------
__global__ __launch_bounds__(512) void binspmm0_kernel(
    const unsigned long long* __restrict__ binbuf,
    const int* __restrict__ bintotal,
    unsigned long long* __restrict__ sortbuf,
    int* __restrict__ rowstart, int* __restrict__ rowcnt,
    const float* __restrict__ src,
    const float* __restrict__ b1, const float* __restrict__ right,
    float* __restrict__ dst, int n)
{
    __shared__ unsigned long long sorted[BCAP];   // 18944 B
    __shared__ int hcnt[RPB];
    __shared__ int hstart[RPB];
    __shared__ int hcur[RPB];
    const int bin = blockIdx.x;
    const int tid = threadIdx.x;

    if (tid < RPB) hcnt[tid] = 0;
    __syncthreads();

    int total = bintotal[bin];
    if (total > BCAP) total = BCAP;
    const unsigned long long* bb = binbuf + (size_t)bin * BCAP;

    // pass a: load edges into named regs (<=5) + per-row histogram
    const int s0 = tid, s1 = tid + 512, s2 = tid + 1024, s3 = tid + 1536, s4 = tid + 2048;
    unsigned long long e0 = 0, e1 = 0, e2 = 0, e3 = 0, e4 = 0;
    if (s0 < total) { e0 = bb[s0]; atomicAdd(&hcnt[(int)((e0 >> 17) & (RPB - 1))], 1); }
    if (s1 < total) { e1 = bb[s1]; atomicAdd(&hcnt[(int)((e1 >> 17) & (RPB - 1))], 1); }
    if (s2 < total) { e2 = bb[s2]; atomicAdd(&hcnt[(int)((e2 >> 17) & (RPB - 1))], 1); }
    if (s3 < total) { e3 = bb[s3]; atomicAdd(&hcnt[(int)((e3 >> 17) & (RPB - 1))], 1); }
    if (s4 < total) { e4 = bb[s4]; atomicAdd(&hcnt[(int)((e4 >> 17) & (RPB - 1))], 1); }
    __syncthreads();

    // pass b: 64-wide exclusive scan
    if (tid < RPB) hstart[tid] = hcnt[tid];
    __syncthreads();
    for (int o = 1; o < RPB; o <<= 1) {
        int t = 0;
        if (tid < RPB) t = hstart[tid] + (tid >= o ? hstart[tid - o] : 0);
        __syncthreads();
        if (tid < RPB) hstart[tid] = t;
        __syncthreads();
    }
    if (tid < RPB) {
        int ex = hstart[tid] - hcnt[tid];
        hstart[tid] = ex;
        hcur[tid] = ex;
    }
    __syncthreads();

    // pass c: scatter from regs into row-sorted LDS
    if (s0 < total) { int rl = (int)((e0 >> 17) & (RPB - 1)); sorted[atomicAdd(&hcur[rl], 1)] = e0; }
    if (s1 < total) { int rl = (int)((e1 >> 17) & (RPB - 1)); sorted[atomicAdd(&hcur[rl], 1)] = e1; }
    if (s2 < total) { int rl = (int)((e2 >> 17) & (RPB - 1)); sorted[atomicAdd(&hcur[rl], 1)] = e2; }
    if (s3 < total) { int rl = (int)((e3 >> 17) & (RPB - 1)); sorted[atomicAdd(&hcur[rl], 1)] = e3; }
    if (s4 < total) { int rl = (int)((e4 >> 17) & (RPB - 1)); sorted[atomicAdd(&hcur[rl], 1)] = e4; }
    __syncthreads();

    // writeback for walk1 (coalesced)
    for (int s = tid; s < total; s += 512)
        sortbuf[(size_t)bin * BCAP + s] = sorted[s];
    if (tid < RPB) {
        rowstart[bin * RPB + tid] = hstart[tid];
        rowcnt[bin * RPB + tid]   = hcnt[tid];
    }

    // pass d: 8 lanes/row, 4-deep batched predicated walk
    const int rl = tid >> 3, l = tid & 7;
    const int st = hstart[rl];
    const int end = st + hcnt[rl];
    float a0 = 0.f, a1 = 0.f, a2 = 0.f, a3 = 0.f;
    float a4 = 0.f, a5 = 0.f, a6 = 0.f, a7 = 0.f;
    for (int i = st + l; i < end; i += 32) {
        const int j1 = i + 8, j2 = i + 16, j3 = i + 24;
        unsigned long long f0 = sorted[i];
        unsigned long long f1 = j1 < end ? sorted[j1] : 0ull;
        unsigned long long f2 = j2 < end ? sorted[j2] : 0ull;
        unsigned long long f3 = j3 < end ? sorted[j3] : 0ull;
        int   c0 = (int)(f0 & 0x1FFFFu); float v0 = __uint_as_float((unsigned)(f0 >> 32));
        int   c1 = (int)(f1 & 0x1FFFFu); float v1 = __uint_as_float((unsigned)(f1 >> 32));
        int   c2 = (int)(f2 & 0x1FFFFu); float v2 = __uint_as_float((unsigned)(f2 >> 32));
        int   c3 = (int)(f3 & 0x1FFFFu); float v3 = __uint_as_float((unsigned)(f3 >> 32));
        const float4* p0 = (const float4*)(src + (size_t)c0 * 8);
        const float4* p1 = (const float4*)(src + (size_t)c1 * 8);
        const float4* p2 = (const float4*)(src + (size_t)c2 * 8);
        const float4* p3 = (const float4*)(src + (size_t)c3 * 8);
        float4 lo0 = p0[0], hi0 = p0[1];
        float4 lo1 = p1[0], hi1 = p1[1];
        float4 lo2 = p2[0], hi2 = p2[1];
        float4 lo3 = p3[0], hi3 = p3[1];
        a0 += v0 * lo0.x; a1 += v0 * lo0.y; a2 += v0 * lo0.z; a3 += v0 * lo0.w;
        a4 += v0 * hi0.x; a5 += v0 * hi0.y; a6 += v0 * hi0.z; a7 += v0 * hi0.w;
        a0 += v1 * lo1.x; a1 += v1 * lo1.y; a2 += v1 * lo1.z; a3 += v1 * lo1.w;
        a4 += v1 * hi1.x; a5 += v1 * hi1.y; a6 += v1 * hi1.z; a7 += v1 * hi1.w;
        a0 += v2 * lo2.x; a1 += v2 * lo2.y; a2 += v2 * lo2.z; a3 += v2 * lo2.w;
        a4 += v2 * hi2.x; a5 += v2 * hi2.y; a6 += v2 * hi2.z; a7 += v2 * hi2.w;
        a0 += v3 * lo3.x; a1 += v3 * lo3.y; a2 += v3 * lo3.z; a3 += v3 * lo3.w;
        a4 += v3 * hi3.x; a5 += v3 * hi3.y; a6 += v3 * hi3.z; a7 += v3 * hi3.w;
    }
#pragma unroll
    for (int o2 = 1; o2 < 8; o2 <<= 1) {
        a0 += __shfl_xor(a0, o2); a1 += __shfl_xor(a1, o2);
        a2 += __shfl_xor(a2, o2); a3 += __shfl_xor(a3, o2);
        a4 += __shfl_xor(a4, o2); a5 += __shfl_xor(a5, o2);
        a6 += __shfl_xor(a6, o2); a7 += __shfl_xor(a7, o2);
    }

    const int g = bin * RPB + rl;
    if (g >= n) return;

    // lane l owns h feature l
    float s = l < 4 ? (l < 2 ? (l == 0 ? a0 : a1) : (l == 2 ? a2 : a3))
                    : (l < 6 ? (l == 4 ? a4 : a5) : (l == 6 ? a6 : a7));
    float hv = 0.5f * fmaxf(s + b1[l], 0.f) + right[(size_t)g * 8 + l];
    dst[(size_t)g * 8 + l] = hv;
}

// ---------------- walk1: batched walk over pre-sorted edges + parallel epilogue ----------------
__global__ __launch_bounds__(512) void walk1_kernel(
    const unsigned long long* __restrict__ sortbuf,
    const int* __restrict__ rowstart, const int* __restrict__ rowcnt,
    const float* __restrict__ src,
    const float* __restrict__ W2, const float* __restrict__ b2,
    float* __restrict__ out, int n)
{
    const int bin = blockIdx.x;
    const int tid = threadIdx.x;
    const int rl = tid >> 3, l = tid & 7;     // 64 rows x 8 lanes

    const int st = rowstart[bin * RPB + rl];
    const int end = st + rowcnt[bin * RPB + rl];
    const unsigned long long* bb = sortbuf + (size_t)bin * BCAP;

    float a0 = 0.f, a1 = 0.f, a2 = 0.f, a3 = 0.f;
    float a4 = 0.f, a5 = 0.f, a6 = 0.f, a7 = 0.f;
    for (int i = st + l; i < end; i += 32) {
        const int j1 = i + 8, j2 = i + 16, j3 = i + 24;
        unsigned long long f0 = bb[i];
        unsigned long long f1 = j1 < end ? bb[j1] : 0ull;
        unsigned long long f2 = j2 < end ? bb[j2] : 0ull;
        unsigned long long f3 = j3 < end ? bb[j3] : 0ull;
        int   c0 = (int)(f0 & 0x1FFFFu); float v0 = __uint_as_float((unsigned)(f0 >> 32));
        int   c1 = (int)(f1 & 0x1FFFFu); float v1 = __uint_as_float((unsigned)(f1 >> 32));
        int   c2 = (int)(f2 & 0x1FFFFu); float v2 = __uint_as_float((unsigned)(f2 >> 32));
        int   c3 = (int)(f3 & 0x1FFFFu); float v3 = __uint_as_float((unsigned)(f3 >> 32));
        const float4* p0 = (const float4*)(src + (size_t)c0 * 8);
        const float4* p1 = (const float4*)(src + (size_t)c1 * 8);
        const float4* p2 = (const float4*)(src + (size_t)c2 * 8);
        const float4* p3 = (const float4*)(src + (size_t)c3 * 8);
        float4 lo0 = p0[0], hi0 = p0[1];
        float4 lo1 = p1[0], hi1 = p1[1];
        float4 lo2 = p2[0], hi2 = p2[1];
        float4 lo3 = p3[0], hi3 = p3[1];
        a0 += v0 * lo0.x; a1 += v0 * lo0.y; a2 += v0 * lo0.z; a3 += v0 * lo0.w;
        a4 += v0 * hi0.x; a5 += v0 * hi0.y; a6 += v0 * hi0.z; a7 += v0 * hi0.w;
        a0 += v1 * lo1.x; a1 += v1 * lo1.y; a2 += v1 * lo1.z; a3 += v1 * lo1.w;
        a4 += v1 * hi1.x; a5 += v1 * hi1.y; a6 += v1 * hi1.z; a7 += v1 * hi1.w;
        a0 += v2 * lo2.x; a1 += v2 * lo2.y; a2 += v2 * lo2.z; a3 += v2 * lo2.w;
        a4 += v2 * hi2.x; a5 += v2 * hi2.y; a6 += v2 * hi2.z; a7 += v2 * hi2.w;
        a0 += v3 * lo3.x; a1 += v3 * lo3.y; a2 += v3 * lo3.z; a3 += v3 * lo3.w;
        a4 += v3 * hi3.x; a5 += v3 * hi3.y; a6 += v3 * hi3.z; a7 += v3 * hi3.w;
    }
#pragma unroll
    for (int o2 = 1; o2 < 8; o2 <<= 1) {
        a0 += __shfl_xor(a0, o2); a1 += __shfl_xor(a1, o2);
        a2 += __shfl_xor(a2, o2); a3 += __shfl_xor(a3, o2);
        a4 += __shfl_xor(a4, o2); a5 += __shfl_xor(a5, o2);
        a6 += __shfl_xor(a6, o2); a7 += __shfl_xor(a7, o2);
    }

    const int g = bin * RPB + rl;
    if (g >= n) return;

    // epilogue: lane l computes classes 2l, 2l+1 of z = h@W2 + b2
    float hv[NHID] = {a0, a1, a2, a3, a4, a5, a6, a7};
    float z0 = b2[2 * l], z1 = b2[2 * l + 1];
#pragma unroll
    for (int j = 0; j < NHID; ++j) {
        float2 w = *(const float2*)(W2 + j * NCLASS + 2 * l);
        z0 += hv[j] * w.x;
        z1 += hv[j] * w.y;
    }
    // 8-lane log-softmax
    float m = fmaxf(z0, z1);
#pragma unroll
    for (int o2 = 1; o2 < 8; o2 <<= 1) m = fmaxf(m, __shfl_xor(m, o2));
    float s = __expf(z0 - m) + __expf(z1 - m);
#pragma unroll
    for (int o2 = 1; o2 < 8; o2 <<= 1) s += __shfl_xor(s, o2);
    float lse = m + __logf(s);
    *(float2*)(out + (size_t)g * NCLASS + 2 * l) = make_float2(z0 - lse, z1 - lse);
}

// ---------------- fallback path ----------------
__global__ __launch_bounds__(256) void prep_kernel(
    const float* __restrict__ W1, const float* __restrict__ V,
    float* __restrict__ W1T, float* __restrict__ VT, float* __restrict__ VSQT,
    uint4* __restrict__ zero_base, int zero_count16)
{
    int tid = blockIdx.x * 256 + threadIdx.x;
    if (tid < NFEAT * NHID) {
        int k = tid >> 3, j = tid & 7;
        W1T[j * NFEAT + k] = W1[tid];
        float vv = V[tid];
        VT[j * NFEAT + k] = vv;
        VSQT[j * NFEAT + k] = vv * vv;
    }
    int stride = gridDim.x * 256;
    for (int i = tid; i < zero_count16; i += stride)
        zero_base[i] = make_uint4(0u, 0u, 0u, 0u);
}

__global__ __launch_bounds__(256) void spmm8_kernel(
    const int* __restrict__ rows, const int* __restrict__ cols,
    const float* __restrict__ vals, const float* __restrict__ src,
    float* __restrict__ acc, int n_edges)
{
    int tid = blockIdx.x * 256 + threadIdx.x;
    int e = tid >> 1;
    if (e >= n_edges) return;
    int hh = tid & 1;
    int r = rows[e], c = cols[e];
    float v = vals[e];
    float4 f = ((const float4*)src)[c * 2 + hh];
    float* d = acc + (size_t)r * NHID + hh * 4;
    unsafeAtomicAdd(d + 0, v * f.x);
    unsafeAtomicAdd(d + 1, v * f.y);
    unsafeAtomicAdd(d + 2, v * f.z);
    unsafeAtomicAdd(d + 3, v * f.w);
}

__global__ __launch_bounds__(256) void mid_kernel(
    const float* __restrict__ acc1, const float* __restrict__ right,
    const float* __restrict__ b1, float* __restrict__ h, int n4)
{
    int i = blockIdx.x * 256 + threadIdx.x;
    if (i >= n4) return;
    float4 a = ((const float4*)acc1)[i];
    float4 r = ((const float4*)right)[i];
    float4 b = ((const float4*)b1)[i & 1];
    float4 o;
    o.x = 0.5f * fmaxf(a.x + b.x, 0.f) + r.x;
    o.y = 0.5f * fmaxf(a.y + b.y, 0.f) + r.y;
    o.z = 0.5f * fmaxf(a.z + b.z, 0.f) + r.z;
    o.w = 0.5f * fmaxf(a.w + b.w, 0.f) + r.w;
    ((float4*)h)[i] = o;
}

__global__ __launch_bounds__(256) void final_kernel(
    const float* __restrict__ acc2, const float* __restrict__ W2,
    const float* __restrict__ b2, float* __restrict__ out, int n_nodes)
{
    int node = blockIdx.x * 256 + threadIdx.x;
    if (node >= n_nodes) return;
    float4 h0 = ((const float4*)acc2)[(size_t)node * 2];
    float4 h1 = ((const float4*)acc2)[(size_t)node * 2 + 1];
    float hv[NHID] = {h0.x, h0.y, h0.z, h0.w, h1.x, h1.y, h1.z, h1.w};
    float z[NCLASS];
#pragma unroll
    for (int c = 0; c < NCLASS; ++c) z[c] = b2[c];
#pragma unroll
    for (int j = 0; j < NHID; ++j) {
#pragma unroll
        for (int c = 0; c < NCLASS; ++c) z[c] += hv[j] * W2[j * NCLASS + c];
    }
    float m = z[0];
#pragma unroll
    for (int c = 1; c < NCLASS; ++c) m = fmaxf(m, z[c]);
    float s = 0.f;
#pragma unroll
    for (int c = 0; c < NCLASS; ++c) s += __expf(z[c] - m);
    float l = m + __logf(s);
    float4* o = (float4*)(out + (size_t)node * NCLASS);
#pragma unroll
    for (int q = 0; q < 4; ++q) {
        float4 tq;
        tq.x = z[4 * q + 0] - l;
        tq.y = z[4 * q + 1] - l;
        tq.z = z[4 * q + 2] - l;
        tq.w = z[4 * q + 3] - l;
        o[q] = tq;
    }
}

extern "C" void kernel_launch(void* const* d_in, const int* in_sizes, int n_in,
                              void* d_out, int out_size, void* d_ws, size_t ws_size,
                              hipStream_t stream)
{
    const float* x     = (const float*)d_in[0];
    const int*   rows  = (const int*)  d_in[1];
    const int*   cols  = (const int*)  d_in[2];
    const float* vals  = (const float*)d_in[3];
    const float* W1    = (const float*)d_in[4];
    const float* b1    = (const float*)d_in[5];
    const float* W2    = (const float*)d_in[6];
    const float* b2    = (const float*)d_in[7];
    const float* V     = (const float*)d_in[8];
    const float* gamma = (const float*)d_in[9];
    const float* beta  = (const float*)d_in[10];

    const int n = in_sizes[0] / NFEAT;   // 100000
    const int e = in_sizes[1];           // 3200000
    const int nbins = (n + RPB - 1) / RPB;             // 1563
    const int dblocks = (n + DB_NODES - 1) / DB_NODES; // 1563

    float* ws = (float*)d_ws;

    // ---- fast-path layout (floats) ----
    float* xw1   = ws;                         // n*8
    float* right = ws + (size_t)n * 8;         // n*8
    float* h     = ws + (size_t)n * 16;        // n*8
    float* W1T   = ws + (size_t)n * 24;        // 4096
    float* VT    = W1T + NFEAT * NHID;
    float* VSQT  = VT + NFEAT * NHID;
    const size_t fixedf = (size_t)n * 24 + 3 * NFEAT * NHID;
    int* hist     = (int*)(ws + fixedf);                       // nbins*NB
    int* off      = hist + (size_t)nbins * NB;                 // nbins*NB
    int* bintotal = off + (size_t)nbins * NB;                  // nbins
    int* rowstart = bintotal + nbins;                          // nbins*RPB
    int* rowcnt   = rowstart + (size_t)nbins * RPB;            // nbins*RPB
    size_t bb_off = (fixedf + 2ull * nbins * NB + nbins + 2ull * nbins * RPB + 1)
                    & ~(size_t)1;
    unsigned long long* binbuf  = (unsigned long long*)(ws + bb_off);
    unsigned long long* sortbuf = binbuf + (size_t)nbins * BCAP;

    const size_t needf = bb_off + 4ull * nbins * BCAP;
    const bool use_fast =
        (n <= (1 << 17)) && (nbins <= NBINS_MAX) && (needf * 4 <= ws_size);

    if (use_fast) {
        // chunk: multiple of 4 so int4/float4 edge loads stay 16B-aligned
        int chunk = ((e + NB - 1) / NB + 3) & ~3;

        count_prep_kernel<<<NB, 256, 0, stream>>>(
            rows, hist, chunk, nbins, e, W1, V, W1T, VT, VSQT);

        scan_kernel<<<nbins, NB, 0, stream>>>(hist, off, bintotal);

        place_dense_kernel<<<dblocks + NB, 256, 0, stream>>>(
            rows, cols, vals, off, binbuf, chunk, nbins, e,
            x, W1T, VT, VSQT, gamma, beta, xw1, right, n, dblocks);

        binspmm0_kernel<<<nbins, 512, 0, stream>>>(
            binbuf, bintotal, sortbuf, rowstart, rowcnt,
            xw1, b1, right, h, n);

        walk1_kernel<<<nbins, 512, 0, stream>>>(
            sortbuf, rowstart, rowcnt, h, W2, b2, (float*)d_out, n);
    } else {
        // fallback: atomic spmm path (acc1/acc2 lead the ws)
        float* f_acc1  = ws;
        float* f_acc2  = ws + (size_t)n * 8;
        float* f_xw1   = ws + (size_t)n * 16;
        float* f_right = ws + (size_t)n * 24;
        float* f_h     = ws + (size_t)n * 32;
        float* f_W1T   = ws + (size_t)n * 40;
        float* f_VT    = f_W1T + NFEAT * NHID;
        float* f_VSQT  = f_VT + NFEAT * NHID;

        prep_kernel<<<(n * 4 + 255) / 256, 256, 0, stream>>>(
            W1, V, f_W1T, f_VT, f_VSQT, (uint4*)ws, n * 4);

        dense_kernel<<<dblocks, 256, 0, stream>>>(
            x, f_W1T, f_VT, f_VSQT, gamma, beta, f_xw1, f_right, n);

        spmm8_kernel<<<(e * 2 + 255) / 256, 256, 0, stream>>>(rows, cols, vals, f_xw1, f_acc1, e);
        mid_kernel<<<(n * 2 + 255) / 256, 256, 0, stream>>>(f_acc1, f_right, b1, f_h, n * 2);
        spmm8_kernel<<<(e * 2 + 255) / 256, 256, 0, stream>>>(rows, cols, vals, f_h, f_acc2, e);
        final_kernel<<<(n + 255) / 256, 256, 0, stream>>>(f_acc2, W2, b2, (float*)d_out, n);
    }
}